// Round 14
// baseline (564.149 us; speedup 1.0000x reference)
//
#include <hip/hip_runtime.h>
#include <hip/hip_cooperative_groups.h>

namespace cg = cooperative_groups;

#define NN 100000
#define NE 1600000
#define D 128
#define KTOT 384          // fp16 single-precision: [b1(h) | b2(nb1) | b3(nb2)]
#define LN_EPS 1e-5f

#define PITCH_US 200      // ushorts per staged row (192 + 8 pad); 100 dw, 100%32=4
#define PITCH_DW 100
#define GM 64             // rows (nodes) per gemm block

#define SCAN_CHUNK 2048
#define NSB 49            // ceil(NN / SCAN_CHUNK)

#define NBK 196           // dst buckets (dst >> 9), 512 nodes each
#define BCAP 10240        // slots per bucket (avg fill 8.2K, sigma ~90)

#define HOPS_GRID 1792    // cooperative: 7 blocks/CU (capacity 8) — co-residency safe
#define HOPS_WAVES (HOPS_GRID * 4)

// front kernel block ranges
#define FB_SCAN1   0                 // [0,49): scan1
#define FB_WEIGHTS 49                // [49,113): weights
#define FB_BIN     113               // [113,895): bin
#define FB_PREP    895               // [895,4020): prep (8 dw/thread)
#define FB_TOTAL   4020

// ---- workspace layout (bytes) ----
#define WS_OFF_OFF   0          // 100352 int (pad absorbs tail writes; chunk-LOCAL excl)
#define WS_OFF_CUR   401408     // 100352 int (fully written by scatter2 writeback)
#define WS_OFF_BSUM  802816     // 64 int (RAW chunk totals from front)
#define WS_OFF_GCUR  803072     // 256 int (memset 0 over [0,196); [200,250) = bsum2 scanned)
#define WS_OFF_WCBF  804096     // 128*384 u16 = 98304, ends 902400
#define WS_OFF_ESRC  967680     // 1.7M int, ends 7767680
#define WS_OFF_H16   7768064    // NN*128 fp16 = 25600000 (permanent, no overlay)
#define WS_OFF_NB1   33368064   // NN*128 fp16 = 25600000 (end 58968064)
#define WS_OFF_GBUF  33368064   // 196*10240*8 = 16056320 — overlays nb1; dead
                                // after scatter2, before hop1 writes nb1

typedef __attribute__((ext_vector_type(8))) _Float16 f16x8;
typedef __attribute__((ext_vector_type(2))) _Float16 f16x2;
typedef __attribute__((ext_vector_type(4))) float f32x4;
typedef __attribute__((ext_vector_type(2))) unsigned int u32x2;   // builtin-compatible 8B

__device__ __forceinline__ unsigned short f2h(float f) {
    _Float16 h = (_Float16)f;                  // v_cvt_f16_f32, RN
    unsigned short s; __builtin_memcpy(&s, &h, 2); return s;
}
__device__ __forceinline__ f16x2 u2h2(unsigned u) {
    f16x2 h; __builtin_memcpy(&h, &u, 4); return h;
}
__device__ __forceinline__ unsigned pk2(float a, float b) {
    return (unsigned)f2h(a) | ((unsigned)f2h(b) << 16);
}

// ---- fused front end: scan1 | weights | bin | prep ----
__global__ __launch_bounds__(256) void k_front(
    const float* __restrict__ deg, int* __restrict__ off, int* __restrict__ bsum,
    const float* __restrict__ Ws, const float* __restrict__ W1,
    const float* __restrict__ Whp, const float* __restrict__ W2,
    const float* __restrict__ logits, unsigned short* __restrict__ wcbf,
    const int* __restrict__ src, const int* __restrict__ dst,
    int* __restrict__ gcur, int2* __restrict__ gbuf,
    const float* __restrict__ h, unsigned int* __restrict__ h16) {
    __shared__ int lds[256];
    __shared__ int bcnt[NBK];
    __shared__ int bbase[NBK];
    const int b = blockIdx.x;
    const int t = threadIdx.x;

    if (b < FB_WEIGHTS) {
        // ================= scan1 (block b): chunk-local exclusive =================
        int base = b * SCAN_CHUNK + t * 8;
        int v[8];
        if (base < NN) {   // NN % 8 == 0
            float4 a0 = reinterpret_cast<const float4*>(deg + base)[0];
            float4 a1 = reinterpret_cast<const float4*>(deg + base)[1];
            v[0] = __float2int_rn(a0.x); v[1] = __float2int_rn(a0.y);
            v[2] = __float2int_rn(a0.z); v[3] = __float2int_rn(a0.w);
            v[4] = __float2int_rn(a1.x); v[5] = __float2int_rn(a1.y);
            v[6] = __float2int_rn(a1.z); v[7] = __float2int_rn(a1.w);
        } else {
            #pragma unroll
            for (int j = 0; j < 8; ++j) v[j] = 0;
        }
        int s = 0;
        #pragma unroll
        for (int j = 0; j < 8; ++j) s += v[j];
        lds[t] = s;
        __syncthreads();
        for (int ofs = 1; ofs < 256; ofs <<= 1) {
            int x = (t >= ofs) ? lds[t - ofs] : 0;
            __syncthreads();
            lds[t] += x;
            __syncthreads();
        }
        int excl = (t == 0) ? 0 : lds[t - 1];
        #pragma unroll
        for (int j = 0; j < 8; ++j) { off[base + j] = excl; excl += v[j]; }
        if (t == 255) bsum[b] = lds[255];
    } else if (b < FB_BIN) {
        // ================= weights =================
        int idx = (b - FB_WEIGHTS) * 256 + t;      // < 65536 exactly
        int o = idx >> 7, k = idx & 127;
        float s0 = 2.f / (1.f + __expf(-logits[0]));
        float s1 = 2.f / (1.f + __expf(-logits[1]));
        float s2 = 2.f / (1.f + __expf(-logits[2]));
        float s3 = 2.f / (1.f + __expf(-logits[3]));
        unsigned short b1 = f2h(s0 * Ws[idx] + s2 * Whp[idx]);
        unsigned short b2 = f2h(s1 * W1[idx] - s2 * Whp[idx]);
        unsigned short b3 = f2h(s3 * W2[idx]);
        size_t base = (size_t)o * KTOT + k;
        wcbf[base]       = b1;   // h
        wcbf[base + 128] = b2;   // nb1
        wcbf[base + 256] = b3;   // nb2
    } else if (b < FB_PREP) {
        // ================= bin =================
        if (t < NBK) bcnt[t] = 0;
        __syncthreads();
        int e0 = (b - FB_BIN) * 2048;
        int s[8], d[8], r[8];
        #pragma unroll
        for (int it = 0; it < 8; ++it) {
            int e = e0 + it * 256 + t;
            bool ok = e < NE;
            s[it] = ok ? src[e] : 0;
            d[it] = ok ? dst[e] : -1;
            r[it] = ok ? atomicAdd(&bcnt[d[it] >> 9], 1) : 0;
        }
        __syncthreads();
        if (t < NBK) bbase[t] = atomicAdd(&gcur[t], bcnt[t]);
        __syncthreads();
        #pragma unroll
        for (int it = 0; it < 8; ++it) {
            if (d[it] >= 0) {
                int bk = d[it] >> 9;
                gbuf[(size_t)bk * BCAP + bbase[bk] + r[it]] = make_int2(s[it], d[it]);
            }
        }
    } else {
        // ================= prep: h fp32 -> h16 packed, 8 dwords/thread ====
        int g2 = (b - FB_PREP) * 256 + t;          // [0, 800000) exactly
        const float4* hv = reinterpret_cast<const float4*>(h) + (size_t)g2 * 4;
        float4 a = hv[0], bb = hv[1], c = hv[2], dd = hv[3];
        uint4 o0, o1;
        o0.x = pk2(a.x, a.y);   o0.y = pk2(a.z, a.w);
        o0.z = pk2(bb.x, bb.y); o0.w = pk2(bb.z, bb.w);
        o1.x = pk2(c.x, c.y);   o1.y = pk2(c.z, c.w);
        o1.z = pk2(dd.x, dd.y); o1.w = pk2(dd.z, dd.w);
        reinterpret_cast<uint4*>(h16)[(size_t)g2 * 2]     = o0;
        reinterpret_cast<uint4*>(h16)[(size_t)g2 * 2 + 1] = o1;
    }
}

// scatter pass B: one block per bucket (512 dst nodes). Per-node ranks in LDS.
// scan2 folded in: wave 0 scans the 49 RAW bsum totals locally (sb for this
// bucket); block 0 additionally publishes the scanned array to bsum2 for hops.
__global__ __launch_bounds__(1024) void k_scatter2(const int2* __restrict__ gbuf,
                                                   const int* __restrict__ gcur,
                                                   const int* __restrict__ off,
                                                   const int* __restrict__ bsum,
                                                   int* __restrict__ bsum2,
                                                   int* __restrict__ cur,
                                                   int* __restrict__ esrc) {
    __shared__ int lcur[512];
    __shared__ int sb_sh;
    int b = blockIdx.x;
    int base = b << 9;
    int t = threadIdx.x;
    if (t < 64) {   // wave 0: exclusive scan of raw chunk totals
        int v = (t < NSB) ? bsum[t] : 0;
        #pragma unroll
        for (int ofs = 1; ofs < 64; ofs <<= 1) {
            int x = __shfl_up(v, ofs, 64);
            if (t >= ofs) v += x;
        }
        int excl = __shfl_up(v, 1, 64);
        if (t == 0) excl = 0;
        if (t == (b >> 2)) sb_sh = excl;           // 512*4 = 2048-aligned buckets
        if (b == 0 && t < NSB) bsum2[t] = excl;    // publish for hops
    }
    if (t < 512) lcur[t] = 0;
    __syncthreads();
    int nb = gcur[b];
    int sb = sb_sh;
    const int2* bb = gbuf + (size_t)b * BCAP;
    for (int i = t; i < nb; i += 1024) {
        int2 e = bb[i];
        int p = off[e.y] + sb + atomicAdd(&lcur[e.y - base], 1);
        esrc[p] = e.x;
    }
    __syncthreads();
    if (t < 512) cur[base + t] = lcur[t];
}

// hop body: one wave per node; lane owns 2 dims packed in one dword (fp16 pair).
// 16-wide predicated steps, MLP=16, no serial tail. (At fabric plateau.)
__device__ __forceinline__ void hop_body(int w, int lane, bool interleaved,
                                         const unsigned int* __restrict__ in,
                                         unsigned int* __restrict__ outp,
                                         const int* __restrict__ off,
                                         const int* __restrict__ bsum2,
                                         const int* __restrict__ cnt_arr,
                                         const int* __restrict__ esrc,
                                         const float* __restrict__ deg) {
    int beg = __builtin_amdgcn_readfirstlane(off[w] + bsum2[w >> 11]);
    int cnt = __builtin_amdgcn_readfirstlane(cnt_arr[w]);
    float ax = 0.f, ay = 0.f;
    for (int bs = 0; bs < cnt; bs += 64) {
        int m = cnt - bs; if (m > 64) m = 64;
        int ev = esrc[beg + bs + (lane < m ? lane : 0)];
        for (int j = 0; j < m; j += 16) {
            unsigned u[16];
            #pragma unroll
            for (int k = 0; k < 16; ++k) {
                int idx = j + k;                               // wave-uniform
                int s = __builtin_amdgcn_readlane(ev, idx < m ? idx : 0);
                u[k] = in[(size_t)s * 64 + lane];              // SGPR base + lane
            }
            #pragma unroll
            for (int k = 0; k < 16; ++k) {
                if (j + k >= m) u[k] = 0u;                     // uniform cond
                f16x2 v = u2h2(u[k]);
                ax += (float)v.x; ay += (float)v.y;
            }
        }
    }
    float inv = 1.0f / deg[w];
    ax *= inv; ay *= inv;
    unsigned pk = (unsigned)f2h(ax) | ((unsigned)f2h(ay) << 16);
    if (interleaved) outp[(size_t)w * 128 + 64 + lane] = pk;
    else             outp[(size_t)w * 64 + lane] = pk;
}

// cooperative fused hops: hop1 (h16 -> nb1), grid.sync, hop2 (nb1 -> out 2nd half).
// 1792 blocks x 256 threads = 7168 waves, grid-stride over 100000 nodes.
__global__ __launch_bounds__(256) void k_hops(const unsigned int* __restrict__ h16,
                                              unsigned int* __restrict__ nb1u,
                                              unsigned int* __restrict__ outp,
                                              const int* __restrict__ off,
                                              const int* __restrict__ bsum2,
                                              const int* __restrict__ cnt_arr,
                                              const int* __restrict__ esrc,
                                              const float* __restrict__ deg) {
    cg::grid_group grid = cg::this_grid();
    int wid0 = (blockIdx.x * 256 + threadIdx.x) >> 6;
    int lane = threadIdx.x & 63;
    for (int w = wid0; w < NN; w += HOPS_WAVES)
        hop_body(w, lane, false, h16, nb1u, off, bsum2, cnt_arr, esrc, deg);
    grid.sync();
    for (int w = wid0; w < NN; w += HOPS_WAVES)
        hop_body(w, lane, true, nb1u, outp, off, bsum2, cnt_arr, esrc, deg);
}

// MFMA GEMM (M=64/block, N=128, K=384 in two 192-K LDS chunks) + fused LN.
// Chunk 0 = [h | nb1[0:64]], chunk 1 = [nb1[64:128] | nb2]  (matches wcbf order).
// T14 async-stage: chunk-1 globals prefetched to regs before chunk-0 MFMA.
// uint2-shape staging via clang ext-vector u32x2; all streams nontemporal.
__global__ __launch_bounds__(256) void k_gemm_ln(
    const unsigned int* __restrict__ h16,
    const unsigned int* __restrict__ nb1u,
    const unsigned short* __restrict__ wcbf, const float* __restrict__ bias,
    const float* __restrict__ gamma, const float* __restrict__ beta,
    float* __restrict__ out) {
    __shared__ __align__(16) unsigned short Xs[GM * PITCH_US];   // 25600 B
    __shared__ float part_s[4][GM];
    __shared__ float part_q[4][GM];
    __shared__ float mu_s[GM], rs_s[GM];
    unsigned int* Xs_u = reinterpret_cast<unsigned int*>(Xs);
    const u32x2* h16v = reinterpret_cast<const u32x2*>(h16);
    const u32x2* nb1v = reinterpret_cast<const u32x2*>(nb1u);
    const u32x2* outv = reinterpret_cast<const u32x2*>(out);

    const int t = threadIdx.x;
    const int wv = t >> 6, lane = t & 63;
    const int lm = lane & 15, quad = lane >> 4;
    const int node0 = blockIdx.x * GM;
    const int obase = wv * 32;

    f32x4 acc[4][2] = {};

    // ---- stage chunk 0: h (dw 0..63), nb1[0:32dw] (64..95) — 8B units
    #pragma unroll
    for (int it = 0; it < 8; ++it) {
        int i = t + 256 * it;              // 0..2047 (u32x2 units)
        int row = i >> 5, dp = i & 31;
        int rn = node0 + row; rn = rn < NN ? rn : NN - 1;
        u32x2 v = __builtin_nontemporal_load(&h16v[(size_t)rn * 32 + dp]);
        *reinterpret_cast<u32x2*>(&Xs_u[row * PITCH_DW + dp * 2]) = v;
    }
    #pragma unroll
    for (int it = 0; it < 4; ++it) {
        int i = t + 256 * it;              // 0..1023
        int row = i >> 4, dp = i & 15;
        int rn = node0 + row; rn = rn < NN ? rn : NN - 1;
        u32x2 v = __builtin_nontemporal_load(&nb1v[(size_t)rn * 32 + dp]);
        *reinterpret_cast<u32x2*>(&Xs_u[row * PITCH_DW + 64 + dp * 2]) = v;
    }
    __syncthreads();

    // ---- prefetch chunk 1 into registers (loads in flight across chunk-0 MFMA)
    u32x2 pre1[4], pre2[8];
    #pragma unroll
    for (int it = 0; it < 4; ++it) {
        int i = t + 256 * it;
        int row = i >> 4, dp = i & 15;
        int rn = node0 + row; rn = rn < NN ? rn : NN - 1;
        pre1[it] = __builtin_nontemporal_load(&nb1v[(size_t)rn * 32 + 16 + dp]);
    }
    #pragma unroll
    for (int it = 0; it < 8; ++it) {
        int i = t + 256 * it;
        int row = i >> 5, dp = i & 31;
        int rn = node0 + row; rn = rn < NN ? rn : NN - 1;
        pre2[it] = __builtin_nontemporal_load(&outv[(size_t)rn * 64 + 32 + dp]);
    }

    // ---- chunk 0 compute
    {
        f16x8 bfr[2][6];
        #pragma unroll
        for (int nt = 0; nt < 2; ++nt) {
            const unsigned short* wp =
                wcbf + (size_t)(obase + nt * 16 + lm) * KTOT + quad * 8;
            #pragma unroll
            for (int s = 0; s < 6; ++s)
                bfr[nt][s] = *reinterpret_cast<const f16x8*>(wp + s * 32);
        }
        #pragma unroll
        for (int s = 0; s < 6; ++s) {
            int koff = s * 32 + quad * 8;
            f16x8 a[4];
            #pragma unroll
            for (int mt = 0; mt < 4; ++mt)
                a[mt] = *reinterpret_cast<const f16x8*>(&Xs[(mt * 16 + lm) * PITCH_US + koff]);
            #pragma unroll
            for (int mt = 0; mt < 4; ++mt) {
                acc[mt][0] = __builtin_amdgcn_mfma_f32_16x16x32_f16(a[mt], bfr[0][s], acc[mt][0], 0, 0, 0);
                acc[mt][1] = __builtin_amdgcn_mfma_f32_16x16x32_f16(a[mt], bfr[1][s], acc[mt][1], 0, 0, 0);
            }
        }
    }
    __syncthreads();   // all waves done reading chunk-0 LDS

    // ---- write chunk 1 from registers: nb1[32:64dw] (dw 0..31), nb2 (32..95)
    #pragma unroll
    for (int it = 0; it < 4; ++it) {
        int i = t + 256 * it;
        int row = i >> 4, dp = i & 15;
        *reinterpret_cast<u32x2*>(&Xs_u[row * PITCH_DW + dp * 2]) = pre1[it];
    }
    #pragma unroll
    for (int it = 0; it < 8; ++it) {
        int i = t + 256 * it;
        int row = i >> 5, dp = i & 31;
        *reinterpret_cast<u32x2*>(&Xs_u[row * PITCH_DW + 32 + dp * 2]) = pre2[it];
    }
    __syncthreads();

    // ---- chunk 1 compute
    {
        f16x8 bfr[2][6];
        #pragma unroll
        for (int nt = 0; nt < 2; ++nt) {
            const unsigned short* wp =
                wcbf + (size_t)(obase + nt * 16 + lm) * KTOT + 192 + quad * 8;
            #pragma unroll
            for (int s = 0; s < 6; ++s)
                bfr[nt][s] = *reinterpret_cast<const f16x8*>(wp + s * 32);
        }
        #pragma unroll
        for (int s = 0; s < 6; ++s) {
            int koff = s * 32 + quad * 8;
            f16x8 a[4];
            #pragma unroll
            for (int mt = 0; mt < 4; ++mt)
                a[mt] = *reinterpret_cast<const f16x8*>(&Xs[(mt * 16 + lm) * PITCH_US + koff]);
            #pragma unroll
            for (int mt = 0; mt < 4; ++mt) {
                acc[mt][0] = __builtin_amdgcn_mfma_f32_16x16x32_f16(a[mt], bfr[0][s], acc[mt][0], 0, 0, 0);
                acc[mt][1] = __builtin_amdgcn_mfma_f32_16x16x32_f16(a[mt], bfr[1][s], acc[mt][1], 0, 0, 0);
            }
        }
    }

    // ---- LN: add bias; per-row partial sums via lm-butterfly; cross-wave via LDS
    float bv0 = bias[obase + lm], bv1 = bias[obase + 16 + lm];
    #pragma unroll
    for (int mt = 0; mt < 4; ++mt) {
        float s[4], q[4];
        #pragma unroll
        for (int r = 0; r < 4; ++r) {
            float v0 = acc[mt][0][r] + bv0;
            float v1 = acc[mt][1][r] + bv1;
            acc[mt][0][r] = v0;  acc[mt][1][r] = v1;
            s[r] = v0 + v1;
            q[r] = v0 * v0 + v1 * v1;
        }
        #pragma unroll
        for (int off = 1; off < 16; off <<= 1) {
            #pragma unroll
            for (int r = 0; r < 4; ++r) {
                s[r] += __shfl_xor(s[r], off, 64);
                q[r] += __shfl_xor(q[r], off, 64);
            }
        }
        if (lm == 0) {
            #pragma unroll
            for (int r = 0; r < 4; ++r) {
                part_s[wv][mt * 16 + quad * 4 + r] = s[r];
                part_q[wv][mt * 16 + quad * 4 + r] = q[r];
            }
        }
    }
    __syncthreads();
    if (t < GM) {
        float s = part_s[0][t] + part_s[1][t] + part_s[2][t] + part_s[3][t];
        float q = part_q[0][t] + part_q[1][t] + part_q[2][t] + part_q[3][t];
        float m = s * (1.f / 128.f);
        float var = q * (1.f / 128.f) - m * m;
        mu_s[t] = m;
        rs_s[t] = rsqrtf(var + LN_EPS);
    }
    __syncthreads();

    float g0 = gamma[obase + lm], g1 = gamma[obase + 16 + lm];
    float e0 = beta[obase + lm],  e1 = beta[obase + 16 + lm];
    #pragma unroll
    for (int mt = 0; mt < 4; ++mt) {
        #pragma unroll
        for (int r = 0; r < 4; ++r) {
            int lrow = mt * 16 + quad * 4 + r;
            if (node0 + lrow < NN) {
                float mu = mu_s[lrow], rs = rs_s[lrow];
                size_t ro = (size_t)(node0 + lrow) * D;
                __builtin_nontemporal_store((acc[mt][0][r] - mu) * rs * g0 + e0,
                                            &out[ro + obase + lm]);
                __builtin_nontemporal_store((acc[mt][1][r] - mu) * rs * g1 + e1,
                                            &out[ro + obase + 16 + lm]);
            }
        }
    }
}

extern "C" void kernel_launch(void* const* d_in, const int* in_sizes, int n_in,
                              void* d_out, int out_size, void* d_ws, size_t ws_size,
                              hipStream_t stream) {
    const float* h      = (const float*)d_in[0];
    const int*   ei     = (const int*)d_in[1];
    const float* deg    = (const float*)d_in[2];
    const float* Wself  = (const float*)d_in[3];
    const float* Wnb1   = (const float*)d_in[4];
    const float* Whp    = (const float*)d_in[5];
    const float* Wnb2   = (const float*)d_in[6];
    const float* bias   = (const float*)d_in[7];
    const float* logits = (const float*)d_in[8];
    const float* gamma  = (const float*)d_in[9];
    const float* beta   = (const float*)d_in[10];
    float* out = (float*)d_out;

    char* ws = (char*)d_ws;
    int* off                 = (int*)(ws + WS_OFF_OFF);
    int* cur                 = (int*)(ws + WS_OFF_CUR);
    int* bsum                = (int*)(ws + WS_OFF_BSUM);
    int* gcur                = (int*)(ws + WS_OFF_GCUR);
    int* bsum2               = gcur + 200;   // 50 ints, past bin's [0,196)
    unsigned short* wcbf     = (unsigned short*)(ws + WS_OFF_WCBF);
    int* esrc                = (int*)(ws + WS_OFF_ESRC);
    int2* gbuf               = (int2*)(ws + WS_OFF_GBUF);
    unsigned int* h16        = (unsigned int*)(ws + WS_OFF_H16);
    unsigned int* nb1u       = (unsigned int*)(ws + WS_OFF_NB1);

    const int* src = ei;
    const int* dst = ei + NE;

    (void)hipMemsetAsync(gcur, 0, NBK * sizeof(int), stream);

    // fused front end: scan1 | weights | bin | prep — one dispatch
    k_front<<<FB_TOTAL, 256, 0, stream>>>(deg, off, bsum,
                                          Wself, Wnb1, Whp, Wnb2, logits, wcbf,
                                          src, dst, gcur, gbuf, h, h16);
    // scatter (scan2 folded in; publishes bsum2 for hops)
    k_scatter2<<<NBK, 1024, 0, stream>>>(gbuf, gcur, off, bsum, bsum2, cur, esrc);

    // cooperative fused hops: hop1 -> grid.sync -> hop2
    unsigned int* outu = (unsigned int*)out;
    void* cargs[] = { (void*)&h16, (void*)&nb1u, (void*)&outu, (void*)&off,
                      (void*)&bsum2, (void*)&cur, (void*)&esrc, (void*)&deg };
    (void)hipLaunchCooperativeKernel((void*)k_hops, dim3(HOPS_GRID), dim3(256),
                                     cargs, 0, stream);

    k_gemm_ln<<<(NN + GM - 1) / GM, 256, 0, stream>>>(h16, nb1u, wcbf, bias, gamma, beta, out);
}

// Round 15
// 299.584 us; speedup vs baseline: 1.8831x; 1.8831x over previous
//
#include <hip/hip_runtime.h>

#define NN 100000
#define NE 1600000
#define D 128
#define KTOT 384          // fp16 single-precision: [b1(h) | b2(nb1) | b3(nb2)]
#define LN_EPS 1e-5f

#define PITCH_US 200      // ushorts per staged row (192 + 8 pad); 100 dw, 100%32=4
#define PITCH_DW 100
#define GM 64             // rows (nodes) per gemm block

#define SCAN_CHUNK 2048
#define NSB 49            // ceil(NN / SCAN_CHUNK)

#define NBK 196           // dst buckets (dst >> 9), 512 nodes each
#define BCAP 10240        // slots per bucket (avg fill 8.2K, sigma ~90)

// front kernel block ranges
#define FB_SCAN1   0                 // [0,49): scan1
#define FB_WEIGHTS 49                // [49,113): weights
#define FB_BIN     113               // [113,895): bin
#define FB_PREP    895               // [895,4020): prep (8 dw/thread)
#define FB_TOTAL   4020

// ---- workspace layout (bytes) ----
#define WS_OFF_OFF   0          // 100352 int (pad absorbs tail writes; chunk-LOCAL excl)
#define WS_OFF_CUR   401408     // 100352 int (fully written by scatter2 writeback)
#define WS_OFF_BSUM  802816     // 64 int (RAW chunk totals from front)
#define WS_OFF_GCUR  803072     // 256 int (memset 0 over [0,196); [200,250) = bsum2 scanned)
#define WS_OFF_WCBF  804096     // 128*384 u16 = 98304, ends 902400
#define WS_OFF_ESRC  967680     // 1.7M int, ends 7767680
#define WS_OFF_H16   7768064    // NN*128 fp16 = 25600000 (permanent, no overlay)
#define WS_OFF_NB1   33368064   // NN*128 fp16 = 25600000 (end 58968064)
#define WS_OFF_GBUF  33368064   // 196*10240*8 = 16056320 — overlays nb1; dead
                                // after scatter2, before hop1 writes nb1

typedef __attribute__((ext_vector_type(8))) _Float16 f16x8;
typedef __attribute__((ext_vector_type(2))) _Float16 f16x2;
typedef __attribute__((ext_vector_type(4))) float f32x4;
typedef __attribute__((ext_vector_type(2))) unsigned int u32x2;   // builtin-compatible 8B

__device__ __forceinline__ unsigned short f2h(float f) {
    _Float16 h = (_Float16)f;                  // v_cvt_f16_f32, RN
    unsigned short s; __builtin_memcpy(&s, &h, 2); return s;
}
__device__ __forceinline__ f16x2 u2h2(unsigned u) {
    f16x2 h; __builtin_memcpy(&h, &u, 4); return h;
}
__device__ __forceinline__ unsigned pk2(float a, float b) {
    return (unsigned)f2h(a) | ((unsigned)f2h(b) << 16);
}

// ---- fused front end: scan1 | weights | bin | prep ----
__global__ __launch_bounds__(256) void k_front(
    const float* __restrict__ deg, int* __restrict__ off, int* __restrict__ bsum,
    const float* __restrict__ Ws, const float* __restrict__ W1,
    const float* __restrict__ Whp, const float* __restrict__ W2,
    const float* __restrict__ logits, unsigned short* __restrict__ wcbf,
    const int* __restrict__ src, const int* __restrict__ dst,
    int* __restrict__ gcur, int2* __restrict__ gbuf,
    const float* __restrict__ h, unsigned int* __restrict__ h16) {
    __shared__ int lds[256];
    __shared__ int bcnt[NBK];
    __shared__ int bbase[NBK];
    const int b = blockIdx.x;
    const int t = threadIdx.x;

    if (b < FB_WEIGHTS) {
        // ================= scan1 (block b): chunk-local exclusive =================
        int base = b * SCAN_CHUNK + t * 8;
        int v[8];
        if (base < NN) {   // NN % 8 == 0
            float4 a0 = reinterpret_cast<const float4*>(deg + base)[0];
            float4 a1 = reinterpret_cast<const float4*>(deg + base)[1];
            v[0] = __float2int_rn(a0.x); v[1] = __float2int_rn(a0.y);
            v[2] = __float2int_rn(a0.z); v[3] = __float2int_rn(a0.w);
            v[4] = __float2int_rn(a1.x); v[5] = __float2int_rn(a1.y);
            v[6] = __float2int_rn(a1.z); v[7] = __float2int_rn(a1.w);
        } else {
            #pragma unroll
            for (int j = 0; j < 8; ++j) v[j] = 0;
        }
        int s = 0;
        #pragma unroll
        for (int j = 0; j < 8; ++j) s += v[j];
        lds[t] = s;
        __syncthreads();
        for (int ofs = 1; ofs < 256; ofs <<= 1) {
            int x = (t >= ofs) ? lds[t - ofs] : 0;
            __syncthreads();
            lds[t] += x;
            __syncthreads();
        }
        int excl = (t == 0) ? 0 : lds[t - 1];
        #pragma unroll
        for (int j = 0; j < 8; ++j) { off[base + j] = excl; excl += v[j]; }
        if (t == 255) bsum[b] = lds[255];
    } else if (b < FB_BIN) {
        // ================= weights =================
        int idx = (b - FB_WEIGHTS) * 256 + t;      // < 65536 exactly
        int o = idx >> 7, k = idx & 127;
        float s0 = 2.f / (1.f + __expf(-logits[0]));
        float s1 = 2.f / (1.f + __expf(-logits[1]));
        float s2 = 2.f / (1.f + __expf(-logits[2]));
        float s3 = 2.f / (1.f + __expf(-logits[3]));
        unsigned short b1 = f2h(s0 * Ws[idx] + s2 * Whp[idx]);
        unsigned short b2 = f2h(s1 * W1[idx] - s2 * Whp[idx]);
        unsigned short b3 = f2h(s3 * W2[idx]);
        size_t base = (size_t)o * KTOT + k;
        wcbf[base]       = b1;   // h
        wcbf[base + 128] = b2;   // nb1
        wcbf[base + 256] = b3;   // nb2
    } else if (b < FB_PREP) {
        // ================= bin =================
        if (t < NBK) bcnt[t] = 0;
        __syncthreads();
        int e0 = (b - FB_BIN) * 2048;
        int s[8], d[8], r[8];
        #pragma unroll
        for (int it = 0; it < 8; ++it) {
            int e = e0 + it * 256 + t;
            bool ok = e < NE;
            s[it] = ok ? src[e] : 0;
            d[it] = ok ? dst[e] : -1;
            r[it] = ok ? atomicAdd(&bcnt[d[it] >> 9], 1) : 0;
        }
        __syncthreads();
        if (t < NBK) bbase[t] = atomicAdd(&gcur[t], bcnt[t]);
        __syncthreads();
        #pragma unroll
        for (int it = 0; it < 8; ++it) {
            if (d[it] >= 0) {
                int bk = d[it] >> 9;
                gbuf[(size_t)bk * BCAP + bbase[bk] + r[it]] = make_int2(s[it], d[it]);
            }
        }
    } else {
        // ================= prep: h fp32 -> h16 packed, 8 dwords/thread ====
        int g2 = (b - FB_PREP) * 256 + t;          // [0, 800000) exactly
        const float4* hv = reinterpret_cast<const float4*>(h) + (size_t)g2 * 4;
        float4 a = hv[0], bb = hv[1], c = hv[2], dd = hv[3];
        uint4 o0, o1;
        o0.x = pk2(a.x, a.y);   o0.y = pk2(a.z, a.w);
        o0.z = pk2(bb.x, bb.y); o0.w = pk2(bb.z, bb.w);
        o1.x = pk2(c.x, c.y);   o1.y = pk2(c.z, c.w);
        o1.z = pk2(dd.x, dd.y); o1.w = pk2(dd.z, dd.w);
        reinterpret_cast<uint4*>(h16)[(size_t)g2 * 2]     = o0;
        reinterpret_cast<uint4*>(h16)[(size_t)g2 * 2 + 1] = o1;
    }
}

// scatter pass B: one block per bucket (512 dst nodes). Per-node ranks in LDS.
// scan2 folded in: wave 0 scans the 49 RAW bsum totals locally (sb for this
// bucket); block 0 additionally publishes the scanned array to bsum2 for hops.
// (Raw bsum comes from the PREVIOUS dispatch — no fences needed.)
__global__ __launch_bounds__(1024) void k_scatter2(const int2* __restrict__ gbuf,
                                                   const int* __restrict__ gcur,
                                                   const int* __restrict__ off,
                                                   const int* __restrict__ bsum,
                                                   int* __restrict__ bsum2,
                                                   int* __restrict__ cur,
                                                   int* __restrict__ esrc) {
    __shared__ int lcur[512];
    __shared__ int sb_sh;
    int b = blockIdx.x;
    int base = b << 9;
    int t = threadIdx.x;
    if (t < 64) {   // wave 0: exclusive scan of raw chunk totals
        int v = (t < NSB) ? bsum[t] : 0;
        #pragma unroll
        for (int ofs = 1; ofs < 64; ofs <<= 1) {
            int x = __shfl_up(v, ofs, 64);
            if (t >= ofs) v += x;
        }
        int excl = __shfl_up(v, 1, 64);
        if (t == 0) excl = 0;
        if (t == (b >> 2)) sb_sh = excl;           // 512*4 = 2048-aligned buckets
        if (b == 0 && t < NSB) bsum2[t] = excl;    // publish for hops
    }
    if (t < 512) lcur[t] = 0;
    __syncthreads();
    int nb = gcur[b];
    int sb = sb_sh;
    const int2* bb = gbuf + (size_t)b * BCAP;
    for (int i = t; i < nb; i += 1024) {
        int2 e = bb[i];
        int p = off[e.y] + sb + atomicAdd(&lcur[e.y - base], 1);
        esrc[p] = e.x;
    }
    __syncthreads();
    if (t < 512) cur[base + t] = lcur[t];
}

// one wave per node; lane owns 2 dims packed in one dword (fp16 pair).
// 16-wide predicated steps, MLP=16, no serial tail. (At fabric plateau —
// 6x-confirmed 58.5 µs / 3.6 TB/s; do NOT restructure: R2/R4/R14 all lost.)
// beg = chunk-local off + scanned chunk base bsum2[w>>11].
template <bool INTERLEAVED>
__global__ __launch_bounds__(256) void k_hop(const unsigned int* __restrict__ in,
                                             unsigned int* __restrict__ outp,
                                             const int* __restrict__ off,
                                             const int* __restrict__ bsum2,
                                             const int* __restrict__ cnt_arr,
                                             const int* __restrict__ esrc,
                                             const float* __restrict__ deg) {
    int w = (blockIdx.x * blockDim.x + threadIdx.x) >> 6;
    int lane = threadIdx.x & 63;
    int beg = __builtin_amdgcn_readfirstlane(off[w] + bsum2[w >> 11]);
    int cnt = __builtin_amdgcn_readfirstlane(cnt_arr[w]);
    float ax = 0.f, ay = 0.f;
    for (int bs = 0; bs < cnt; bs += 64) {
        int m = cnt - bs; if (m > 64) m = 64;
        int ev = esrc[beg + bs + (lane < m ? lane : 0)];
        for (int j = 0; j < m; j += 16) {
            unsigned u[16];
            #pragma unroll
            for (int k = 0; k < 16; ++k) {
                int idx = j + k;                               // wave-uniform
                int s = __builtin_amdgcn_readlane(ev, idx < m ? idx : 0);
                u[k] = in[(size_t)s * 64 + lane];              // SGPR base + lane
            }
            #pragma unroll
            for (int k = 0; k < 16; ++k) {
                if (j + k >= m) u[k] = 0u;                     // uniform cond
                f16x2 v = u2h2(u[k]);
                ax += (float)v.x; ay += (float)v.y;
            }
        }
    }
    float inv = 1.0f / deg[w];
    ax *= inv; ay *= inv;
    unsigned pk = (unsigned)f2h(ax) | ((unsigned)f2h(ay) << 16);
    if (INTERLEAVED) outp[(size_t)w * 128 + 64 + lane] = pk;
    else             outp[(size_t)w * 64 + lane] = pk;
}

// MFMA GEMM (M=64/block, N=128, K=384 in two 192-K LDS chunks) + fused LN.
// Chunk 0 = [h | nb1[0:64]], chunk 1 = [nb1[64:128] | nb2]  (matches wcbf order).
// T14 async-stage: chunk-1 globals prefetched to regs before chunk-0 MFMA.
// uint2-shape staging via clang ext-vector u32x2; all streams nontemporal.
__global__ __launch_bounds__(256) void k_gemm_ln(
    const unsigned int* __restrict__ h16,
    const unsigned int* __restrict__ nb1u,
    const unsigned short* __restrict__ wcbf, const float* __restrict__ bias,
    const float* __restrict__ gamma, const float* __restrict__ beta,
    float* __restrict__ out) {
    __shared__ __align__(16) unsigned short Xs[GM * PITCH_US];   // 25600 B
    __shared__ float part_s[4][GM];
    __shared__ float part_q[4][GM];
    __shared__ float mu_s[GM], rs_s[GM];
    unsigned int* Xs_u = reinterpret_cast<unsigned int*>(Xs);
    const u32x2* h16v = reinterpret_cast<const u32x2*>(h16);
    const u32x2* nb1v = reinterpret_cast<const u32x2*>(nb1u);
    const u32x2* outv = reinterpret_cast<const u32x2*>(out);

    const int t = threadIdx.x;
    const int wv = t >> 6, lane = t & 63;
    const int lm = lane & 15, quad = lane >> 4;
    const int node0 = blockIdx.x * GM;
    const int obase = wv * 32;

    f32x4 acc[4][2] = {};

    // ---- stage chunk 0: h (dw 0..63), nb1[0:32dw] (64..95) — 8B units
    #pragma unroll
    for (int it = 0; it < 8; ++it) {
        int i = t + 256 * it;              // 0..2047 (u32x2 units)
        int row = i >> 5, dp = i & 31;
        int rn = node0 + row; rn = rn < NN ? rn : NN - 1;
        u32x2 v = __builtin_nontemporal_load(&h16v[(size_t)rn * 32 + dp]);
        *reinterpret_cast<u32x2*>(&Xs_u[row * PITCH_DW + dp * 2]) = v;
    }
    #pragma unroll
    for (int it = 0; it < 4; ++it) {
        int i = t + 256 * it;              // 0..1023
        int row = i >> 4, dp = i & 15;
        int rn = node0 + row; rn = rn < NN ? rn : NN - 1;
        u32x2 v = __builtin_nontemporal_load(&nb1v[(size_t)rn * 32 + dp]);
        *reinterpret_cast<u32x2*>(&Xs_u[row * PITCH_DW + 64 + dp * 2]) = v;
    }
    __syncthreads();

    // ---- prefetch chunk 1 into registers (loads in flight across chunk-0 MFMA)
    u32x2 pre1[4], pre2[8];
    #pragma unroll
    for (int it = 0; it < 4; ++it) {
        int i = t + 256 * it;
        int row = i >> 4, dp = i & 15;
        int rn = node0 + row; rn = rn < NN ? rn : NN - 1;
        pre1[it] = __builtin_nontemporal_load(&nb1v[(size_t)rn * 32 + 16 + dp]);
    }
    #pragma unroll
    for (int it = 0; it < 8; ++it) {
        int i = t + 256 * it;
        int row = i >> 5, dp = i & 31;
        int rn = node0 + row; rn = rn < NN ? rn : NN - 1;
        pre2[it] = __builtin_nontemporal_load(&outv[(size_t)rn * 64 + 32 + dp]);
    }

    // ---- chunk 0 compute
    {
        f16x8 bfr[2][6];
        #pragma unroll
        for (int nt = 0; nt < 2; ++nt) {
            const unsigned short* wp =
                wcbf + (size_t)(obase + nt * 16 + lm) * KTOT + quad * 8;
            #pragma unroll
            for (int s = 0; s < 6; ++s)
                bfr[nt][s] = *reinterpret_cast<const f16x8*>(wp + s * 32);
        }
        #pragma unroll
        for (int s = 0; s < 6; ++s) {
            int koff = s * 32 + quad * 8;
            f16x8 a[4];
            #pragma unroll
            for (int mt = 0; mt < 4; ++mt)
                a[mt] = *reinterpret_cast<const f16x8*>(&Xs[(mt * 16 + lm) * PITCH_US + koff]);
            #pragma unroll
            for (int mt = 0; mt < 4; ++mt) {
                acc[mt][0] = __builtin_amdgcn_mfma_f32_16x16x32_f16(a[mt], bfr[0][s], acc[mt][0], 0, 0, 0);
                acc[mt][1] = __builtin_amdgcn_mfma_f32_16x16x32_f16(a[mt], bfr[1][s], acc[mt][1], 0, 0, 0);
            }
        }
    }
    __syncthreads();   // all waves done reading chunk-0 LDS

    // ---- write chunk 1 from registers: nb1[32:64dw] (dw 0..31), nb2 (32..95)
    #pragma unroll
    for (int it = 0; it < 4; ++it) {
        int i = t + 256 * it;
        int row = i >> 4, dp = i & 15;
        *reinterpret_cast<u32x2*>(&Xs_u[row * PITCH_DW + dp * 2]) = pre1[it];
    }
    #pragma unroll
    for (int it = 0; it < 8; ++it) {
        int i = t + 256 * it;
        int row = i >> 5, dp = i & 31;
        *reinterpret_cast<u32x2*>(&Xs_u[row * PITCH_DW + 32 + dp * 2]) = pre2[it];
    }
    __syncthreads();

    // ---- chunk 1 compute
    {
        f16x8 bfr[2][6];
        #pragma unroll
        for (int nt = 0; nt < 2; ++nt) {
            const unsigned short* wp =
                wcbf + (size_t)(obase + nt * 16 + lm) * KTOT + 192 + quad * 8;
            #pragma unroll
            for (int s = 0; s < 6; ++s)
                bfr[nt][s] = *reinterpret_cast<const f16x8*>(wp + s * 32);
        }
        #pragma unroll
        for (int s = 0; s < 6; ++s) {
            int koff = s * 32 + quad * 8;
            f16x8 a[4];
            #pragma unroll
            for (int mt = 0; mt < 4; ++mt)
                a[mt] = *reinterpret_cast<const f16x8*>(&Xs[(mt * 16 + lm) * PITCH_US + koff]);
            #pragma unroll
            for (int mt = 0; mt < 4; ++mt) {
                acc[mt][0] = __builtin_amdgcn_mfma_f32_16x16x32_f16(a[mt], bfr[0][s], acc[mt][0], 0, 0, 0);
                acc[mt][1] = __builtin_amdgcn_mfma_f32_16x16x32_f16(a[mt], bfr[1][s], acc[mt][1], 0, 0, 0);
            }
        }
    }

    // ---- LN: add bias; per-row partial sums via lm-butterfly; cross-wave via LDS
    float bv0 = bias[obase + lm], bv1 = bias[obase + 16 + lm];
    #pragma unroll
    for (int mt = 0; mt < 4; ++mt) {
        float s[4], q[4];
        #pragma unroll
        for (int r = 0; r < 4; ++r) {
            float v0 = acc[mt][0][r] + bv0;
            float v1 = acc[mt][1][r] + bv1;
            acc[mt][0][r] = v0;  acc[mt][1][r] = v1;
            s[r] = v0 + v1;
            q[r] = v0 * v0 + v1 * v1;
        }
        #pragma unroll
        for (int off = 1; off < 16; off <<= 1) {
            #pragma unroll
            for (int r = 0; r < 4; ++r) {
                s[r] += __shfl_xor(s[r], off, 64);
                q[r] += __shfl_xor(q[r], off, 64);
            }
        }
        if (lm == 0) {
            #pragma unroll
            for (int r = 0; r < 4; ++r) {
                part_s[wv][mt * 16 + quad * 4 + r] = s[r];
                part_q[wv][mt * 16 + quad * 4 + r] = q[r];
            }
        }
    }
    __syncthreads();
    if (t < GM) {
        float s = part_s[0][t] + part_s[1][t] + part_s[2][t] + part_s[3][t];
        float q = part_q[0][t] + part_q[1][t] + part_q[2][t] + part_q[3][t];
        float m = s * (1.f / 128.f);
        float var = q * (1.f / 128.f) - m * m;
        mu_s[t] = m;
        rs_s[t] = rsqrtf(var + LN_EPS);
    }
    __syncthreads();

    float g0 = gamma[obase + lm], g1 = gamma[obase + 16 + lm];
    float e0 = beta[obase + lm],  e1 = beta[obase + 16 + lm];
    #pragma unroll
    for (int mt = 0; mt < 4; ++mt) {
        #pragma unroll
        for (int r = 0; r < 4; ++r) {
            int lrow = mt * 16 + quad * 4 + r;
            if (node0 + lrow < NN) {
                float mu = mu_s[lrow], rs = rs_s[lrow];
                size_t ro = (size_t)(node0 + lrow) * D;
                __builtin_nontemporal_store((acc[mt][0][r] - mu) * rs * g0 + e0,
                                            &out[ro + obase + lm]);
                __builtin_nontemporal_store((acc[mt][1][r] - mu) * rs * g1 + e1,
                                            &out[ro + obase + 16 + lm]);
            }
        }
    }
}

extern "C" void kernel_launch(void* const* d_in, const int* in_sizes, int n_in,
                              void* d_out, int out_size, void* d_ws, size_t ws_size,
                              hipStream_t stream) {
    const float* h      = (const float*)d_in[0];
    const int*   ei     = (const int*)d_in[1];
    const float* deg    = (const float*)d_in[2];
    const float* Wself  = (const float*)d_in[3];
    const float* Wnb1   = (const float*)d_in[4];
    const float* Whp    = (const float*)d_in[5];
    const float* Wnb2   = (const float*)d_in[6];
    const float* bias   = (const float*)d_in[7];
    const float* logits = (const float*)d_in[8];
    const float* gamma  = (const float*)d_in[9];
    const float* beta   = (const float*)d_in[10];
    float* out = (float*)d_out;

    char* ws = (char*)d_ws;
    int* off                 = (int*)(ws + WS_OFF_OFF);
    int* cur                 = (int*)(ws + WS_OFF_CUR);
    int* bsum                = (int*)(ws + WS_OFF_BSUM);
    int* gcur                = (int*)(ws + WS_OFF_GCUR);
    int* bsum2               = gcur + 200;   // 50 ints, past bin's [0,196)
    unsigned short* wcbf     = (unsigned short*)(ws + WS_OFF_WCBF);
    int* esrc                = (int*)(ws + WS_OFF_ESRC);
    int2* gbuf               = (int2*)(ws + WS_OFF_GBUF);
    unsigned int* h16        = (unsigned int*)(ws + WS_OFF_H16);
    unsigned int* nb1u       = (unsigned int*)(ws + WS_OFF_NB1);

    const int* src = ei;
    const int* dst = ei + NE;

    (void)hipMemsetAsync(gcur, 0, NBK * sizeof(int), stream);

    // fused front end: scan1 | weights | bin | prep — one dispatch
    k_front<<<FB_TOTAL, 256, 0, stream>>>(deg, off, bsum,
                                          Wself, Wnb1, Whp, Wnb2, logits, wcbf,
                                          src, dst, gcur, gbuf, h, h16);
    // scatter (scan2 folded in; publishes bsum2 for hops)
    k_scatter2<<<NBK, 1024, 0, stream>>>(gbuf, gcur, off, bsum, bsum2, cur, esrc);

    // hop1: gather h (fp16) -> nb1 (fp16, ws; overwrites dead gbuf)
    k_hop<false><<<(NN * 64) / 256, 256, 0, stream>>>(h16, nb1u, off, bsum2, cur, esrc, deg);
    // hop2: gather nb1 (fp16) -> nb2 (fp16, interleaved into out rows' 2nd half)
    k_hop<true><<<(NN * 64) / 256, 256, 0, stream>>>(nb1u, (unsigned int*)out, off, bsum2, cur, esrc, deg);

    k_gemm_ln<<<(NN + GM - 1) / GM, 256, 0, stream>>>(h16, nb1u, wcbf, bias, gamma, beta, out);
}